// Round 5
// baseline (44306.198 us; speedup 1.0000x reference)
//
#include <hip/hip_runtime.h>

typedef __attribute__((ext_vector_type(8))) short s8v;   // 8 x bf16 (4 VGPRs)
typedef __attribute__((ext_vector_type(4))) float f4v;   // f32 MFMA accumulator
typedef __attribute__((ext_vector_type(4))) int   i4v;   // i8 MFMA operand/accumulator

#define BB 8
#define TT 500
#define UU 120
#define UP1 121
#define VV 128
#define HH 320
#define G4 1280

// ---------------- helpers ----------------
__device__ __forceinline__ unsigned short f2bf(float x) {
  unsigned u = __builtin_bit_cast(unsigned, x);
  unsigned r = (u + 0x7FFFu + ((u >> 16) & 1u)) >> 16;  // RNE
  return (unsigned short)r;
}
__device__ __forceinline__ float bf2f(unsigned hi16) {  // hi16 = bf16 in high bits
  return __builtin_bit_cast(float, hi16 & 0xFFFF0000u);
}
__device__ __forceinline__ float sigf(float x)   { return 1.f / (1.f + __expf(-x)); }
__device__ __forceinline__ float tanh_f(float x) { return 2.f / (1.f + __expf(-2.f * x)) - 1.f; }

// relaxed agent-scope atomics (sc1 path; proven transport in r3/r4)
__device__ __forceinline__ unsigned ald32(const unsigned* p) {
  return __hip_atomic_load((unsigned*)p, __ATOMIC_RELAXED, __HIP_MEMORY_SCOPE_AGENT);
}
__device__ __forceinline__ void ast32(unsigned* p, unsigned v) {
  __hip_atomic_store(p, v, __ATOMIC_RELAXED, __HIP_MEMORY_SCOPE_AGENT);
}

// ---------------- prep: zero control words + out ----------------
__global__ void prep_zero(unsigned* ctl, float* out) {
  int i = blockIdx.x * blockDim.x + threadIdx.x;
  if (i < 256) ctl[i] = 0u;          // smax[0..3] at [0..4), prog at [16]
  if (i == 0) out[0] = 0.f;
}

// ---------------- abs-max per recurrent matrix (for i8 scales) ----------------
__global__ __launch_bounds__(256) void k_absmax(
    const float* __restrict__ w0, const float* __restrict__ w1,
    const float* __restrict__ w2, const float* __restrict__ w3,
    unsigned* __restrict__ smax)
{
  const int blk = blockIdx.x;                 // 1600 = 4 mats x 400
  const int s = blk / 400;
  const int off = (blk - s * 400) * 1024 + threadIdx.x * 4;
  const float* src = (s == 0) ? w0 : (s == 1) ? w1 : (s == 2) ? w2 : w3;
  float m = 0.f;
#pragma unroll
  for (int j = 0; j < 4; j++) m = fmaxf(m, fabsf(src[off + j]));
#pragma unroll
  for (int o = 32; o >= 1; o >>= 1) m = fmaxf(m, __shfl_xor(m, o));
  if ((threadIdx.x & 63) == 0) atomicMax(smax + s, __float_as_uint(m));
}

// ---------------- pack recurrent matrices into per-wave i8 MFMA fragment blobs ----------------
// blob[s][w][mt][kt][lane][16] i8 ; s: 0=Whh0 1=Whh1 2=Whhd 3=Wih1
__global__ __launch_bounds__(256) void k_pack(
    const float* __restrict__ w0, const float* __restrict__ w1,
    const float* __restrict__ w2, const float* __restrict__ w3,
    const unsigned* __restrict__ smax, char* __restrict__ wq)
{
  int gid = blockIdx.x * 256 + threadIdx.x;
  if (gid >= 1638400) return;
  int s = gid / 409600, r = gid - s * 409600;
  int j = r & 15, ln = (r >> 4) & 63, rem = r >> 10;
  int kt = rem % 5, mt = (rem / 5) % 10, w = rem / 50;
  int qq = ln >> 4, nn = ln & 15;
  int k = kt * 64 + qq * 16 + j;
  int gr;
  if (s < 3) { int unit = w * 40 + mt * 4 + (nn >> 2); gr = (nn & 3) * HH + unit; }
  else       { gr = w * 160 + mt * 16 + nn; }
  const float* src = (s == 0) ? w0 : (s == 1) ? w1 : (s == 2) ? w2 : w3;
  float inv = 127.f / __uint_as_float(smax[s]);
  wq[gid] = (char)__float2int_rn(src[gr * HH + k] * inv);
}

// ---------------- misc prep: bf16 staging + bias folds ----------------
__global__ void prep_w(
    const float* __restrict__ wih0, const float* __restrict__ xs,
    const float* __restrict__ ewo,  const float* __restrict__ dwo,
    const float* __restrict__ bih1, const float* __restrict__ bhh1,
    const float* __restrict__ bih0, const float* __restrict__ bhh0,
    ushort* __restrict__ wih0b, ushort* __restrict__ xsb,
    ushort* __restrict__ wob, ushort* __restrict__ dwob,
    float* __restrict__ b1s, float* __restrict__ b0s)
{
  int i = blockIdx.x * blockDim.x + threadIdx.x;
  if (i < 122880) {                        // Wih0 [1280][80] -> [1280][96] padded
    int row = i / 96, k = i - row * 96;
    wih0b[i] = (k < 80) ? f2bf(wih0[row * 80 + k]) : (ushort)0;
  } else if (i < 506880) {                 // xs [4000][80] -> [4000][96] padded
    int e = i - 122880;
    int row = e / 96, k = e - row * 96;
    xsb[e] = (k < 80) ? f2bf(xs[row * 80 + k]) : (ushort)0;
  } else if (i < 547840) {                 // enc_Wo [128][320]
    wob[i - 506880] = f2bf(ewo[i - 506880]);
  } else if (i < 588800) {                 // dec_Wo [128][320]
    dwob[i - 547840] = f2bf(dwo[i - 547840]);
  } else if (i < 590080) {                 // b1s[gr] = bih1+bhh1 (gate-row order)
    int e = i - 588800;
    b1s[e] = bih1[e] + bhh1[e];
  } else if (i < 591360) {                 // b0s[gr]
    int e = i - 590080;
    b0s[e] = bih0[e] + bhh0[e];
  }
}

// ---------------- xproj layer0 (bf16 MFMA, r1-verified), output bf16 now ----------------
__global__ __launch_bounds__(256) void xproj0_mfma(
    const ushort* __restrict__ xsb, const ushort* __restrict__ wih0b,
    const float* __restrict__ b0s, ushort* __restrict__ xp0h)
{
  const int mt = blockIdx.x;                 // 250 tiles of 16 (b,t)-rows
  const int wave = threadIdx.x >> 6, lane = threadIdx.x & 63;
  const int q = lane >> 4, n16 = lane & 15;
  s8v a[3];
#pragma unroll
  for (int kt = 0; kt < 3; kt++)
    a[kt] = *(const s8v*)(xsb + (mt * 16 + n16) * 96 + kt * 32 + q * 8);
  for (int nt = wave; nt < 80; nt += 4) {
    s8v bf[3];
#pragma unroll
    for (int kt = 0; kt < 3; kt++)
      bf[kt] = *(const s8v*)(wih0b + (nt * 16 + n16) * 96 + kt * 32 + q * 8);
    f4v acc = {0.f, 0.f, 0.f, 0.f};
#pragma unroll
    for (int kt = 0; kt < 3; kt++)
      acc = __builtin_amdgcn_mfma_f32_16x16x32_bf16(a[kt], bf[kt], acc, 0, 0, 0);
    const int gr = nt * 16 + n16;            // D col = gate row
    const int gg = gr / HH;
    const int uu = gr - gg * HH;
    const float bias = b0s[gr];
#pragma unroll
    for (int r = 0; r < 4; r++) {
      int bt = mt * 16 + 4 * q + r;          // D row = (b,t) row
      xp0h[(size_t)bt * G4 + uu * 4 + gg] = f2bf(acc[r] + bias);
    }
  }
}

// ---------------- decoder input projection: one-hot gather (unchanged) ----------------
__global__ __launch_bounds__(256) void xprojd_g(
    const int* __restrict__ ys, const float* __restrict__ dWih,
    const float* __restrict__ dbih, const float* __restrict__ dbhh,
    float* __restrict__ xpd)
{
  const int blk = blockIdx.x;                // 968 = 8 * 121
  const int b = blk / UP1, u = blk - b * UP1;
  int colv = -1;
  if (u > 0) colv = ys[b * UU + (u - 1)] - 1;
  for (int i = threadIdx.x; i < G4; i += 256) {
    int uu = i >> 2, gg = i & 3;
    int row = gg * HH + uu;
    float v = dbih[row] + dbhh[row];
    if (colv >= 0) v += dWih[row * 127 + colv];
    xpd[((size_t)b * UP1 + u) * G4 + i] = v;
  }
}

// ---------------- fused recurrences: 6 wgs, all recurrences INTRA-workgroup ----------------
// role 0: L0  (i8 Whh0 resident; LDS h ring; publishes h0 tagged u32)
// role 1: L1  (i8 Whh1 resident; consumes z1 ring; publishes h1 plain bf16)
// role 2: dec (i8 Whhd resident; publishes hd plain bf16), 121 steps
// role 3..5: z1 producers (t mod 3): poll h0[t+1] (tagged), z1[t]=Wih1@h0[t+1]+b1 -> ring
__global__ __launch_bounds__(512, 2) void lstm_fused(
    const char* __restrict__ wq, const unsigned* __restrict__ smaxp,
    const ushort* __restrict__ xp0h, const float* __restrict__ xpd,
    const float* __restrict__ b1s,
    unsigned* __restrict__ h0u, ushort* __restrict__ h1h, ushort* __restrict__ hdh,
    unsigned* __restrict__ z1u, unsigned* __restrict__ prog)
{
  const int role = blockIdx.x;
  const int tid = threadIdx.x;
  const int wave = tid >> 6, lane = tid & 63;
  const int q = lane >> 4, n16 = lane & 15;
  const int bcol = n16 & 7;
  const int ub = wave * 40;                  // rec roles: this wave owns units [ub,ub+40)

  __shared__ __align__(16) char wlds[8][6][1024];   // 48 KB: frag-groups gi 0..5 per wave
  __shared__ __align__(16) char hq[2][16][336];     // double-buffered h_i8 (B operand)

  const int mat = (role <= 2) ? role : 3;
  const char* blob = wq + mat * 409600 + wave * 51200;

  // ---- startup: weights into regs (gi 6..49) + LDS (gi 0..5); zero hq ----
  i4v wreg[44];
#pragma unroll
  for (int gi = 6; gi < 50; gi++)
    wreg[gi - 6] = *(const i4v*)(blob + gi * 1024 + lane * 16);
#pragma unroll
  for (int gi = 0; gi < 6; gi++) {
    i4v v = *(const i4v*)(blob + gi * 1024 + lane * 16);
    *(i4v*)(&wlds[wave][gi][lane * 16]) = v;
  }
  for (int i = tid; i < 2688; i += 512) ((unsigned*)hq)[i] = 0u;
  __syncthreads();

  const float kf = __uint_as_float(smaxp[mat]) * (1.f / 16129.f);  // smax/(127*127)

  if (role <= 2) {
    // ================= recurrent stages =================
    const int steps = (role == 2) ? UP1 : TT;
    const ushort* xq0 = xp0h + (size_t)bcol * TT * G4;
    const float*  xqd = xpd  + (size_t)bcol * UP1 * G4;
    float c[10];
#pragma unroll
    for (int m = 0; m < 10; m++) c[m] = 0.f;

    for (int t = 0; t < steps; t++) {
      const int pb = t & 1;
#pragma unroll
      for (int P = 0; P < 2; P++) {
        // P=0: mts 5..9 (all-reg); P=1: mts 0..4 (gi<6 from LDS)
        uint2 xa[5]; f4v xf[5]; unsigned za[5][4];
        if (role == 0) {
#pragma unroll
          for (int mi = 0; mi < 5; mi++) {
            const int m = P ? mi : 5 + mi;
            xa[mi] = *(const uint2*)(xq0 + (size_t)t * G4 + (ub + m * 4 + q) * 4);
          }
        } else if (role == 2) {
#pragma unroll
          for (int mi = 0; mi < 5; mi++) {
            const int m = P ? mi : 5 + mi;
            xf[mi] = *(const f4v*)(xqd + (size_t)t * G4 + (ub + m * 4 + q) * 4);
          }
        } else {
#pragma unroll
          for (int mi = 0; mi < 5; mi++) {
            const int m = P ? mi : 5 + mi;
            const unsigned zb = (unsigned)((t & 127) * 10240 + (ub + m * 4 + q) * 32 + n16 * 4);
#pragma unroll
            for (int g = 0; g < 4; g++) za[mi][g] = ald32(z1u + zb + g);
          }
        }

        i4v acc[5];
#pragma unroll
        for (int mi = 0; mi < 5; mi++) { i4v z = {0,0,0,0}; acc[mi] = z; }
#pragma unroll
        for (int kt = 0; kt < 5; kt++) {
          i4v bf = *(const i4v*)(&hq[pb][n16][kt * 64 + q * 16]);
#pragma unroll
          for (int mi = 0; mi < 5; mi++) {
            const int m = P ? mi : 5 + mi;
            const int gi = m * 5 + kt;
            i4v wf = (gi < 6) ? *(const i4v*)(&wlds[wave][gi][lane * 16]) : wreg[gi - 6];
            acc[mi] = __builtin_amdgcn_mfma_i32_16x16x64_i8(wf, bf, acc[mi], 0, 0, 0);
          }
        }

        if (role == 1) {                      // verify z1 epoch tags (rare re-poll)
          const unsigned tg = (unsigned)((t & 255) + 1);
          int tries = 0;
          for (;;) {
            int ok = 1;
#pragma unroll
            for (int mi = 0; mi < 5; mi++)
#pragma unroll
              for (int g = 0; g < 4; g++) ok &= ((za[mi][g] & 255u) == tg);
            if (n16 >= 8) ok = 1;
            if (__all(ok) || ++tries > (1 << 13)) break;
            __builtin_amdgcn_s_sleep(2);
#pragma unroll
            for (int mi = 0; mi < 5; mi++) {
              const int m = P ? mi : 5 + mi;
              const unsigned zb = (unsigned)((t & 127) * 10240 + (ub + m * 4 + q) * 32 + n16 * 4);
#pragma unroll
              for (int g = 0; g < 4; g++) za[mi][g] = ald32(z1u + zb + g);
            }
          }
        }

        // ---- cell: lane-local (unit = ub+m*4+q, batch n16) ----
#pragma unroll
        for (int mi = 0; mi < 5; mi++) {
          const int m = P ? mi : 5 + mi;
          float ad0, ad1, ad2, ad3;
          if (role == 0) {
            ad0 = bf2f(xa[mi].x << 16); ad1 = bf2f(xa[mi].x);
            ad2 = bf2f(xa[mi].y << 16); ad3 = bf2f(xa[mi].y);
          } else if (role == 1) {
            ad0 = bf2f(za[mi][0]); ad1 = bf2f(za[mi][1]);
            ad2 = bf2f(za[mi][2]); ad3 = bf2f(za[mi][3]);
          } else {
            ad0 = xf[mi][0]; ad1 = xf[mi][1]; ad2 = xf[mi][2]; ad3 = xf[mi][3];
          }
          float p0 = (float)acc[mi][0] * kf + ad0;
          float p1 = (float)acc[mi][1] * kf + ad1;
          float p2 = (float)acc[mi][2] * kf + ad2;
          float p3 = (float)acc[mi][3] * kf + ad3;
          float ig = sigf(p0), fg = sigf(p1), gv = tanh_f(p2), og = sigf(p3);
          c[m] = fg * c[m] + ig * gv;
          float hv = og * tanh_f(c[m]);
          const int u = ub + m * 4 + q;
          hq[pb ^ 1][n16][u] = (char)__float2int_rn(hv * 127.f);
          if (n16 < BB) {
            unsigned hb = (unsigned)f2bf(hv);
            if (role == 0)
              ast32(h0u + (size_t)(t + 1) * 2560 + n16 * HH + u, (hb << 16) | 1u);
            else if (role == 1)
              h1h[(size_t)(t + 1) * 5120 + n16 * HH + u] = (ushort)hb;
            else
              hdh[(size_t)(t + 1) * 5120 + n16 * HH + u] = (ushort)hb;
          }
        }
      }
      // LDS-only barrier: do NOT drain vmcnt (publishes are fire-and-forget)
      asm volatile("s_waitcnt lgkmcnt(0)\n\ts_barrier" ::: "memory");
      if (role == 1 && (t & 31) == 31 && tid == 0) ast32(prog, (unsigned)t);
    }
  } else {
    // ================= z1 producers (t = p, p+3, ...) =================
    const int p3 = role - 3;
    int it = 0;
    for (int t = p3; t < TT; t += 3, it++) {
      const int buf = it & 1;
      // throttle vs L1 consumption (ring safety; usually instant)
      { int tr = 0;
        while ((int)ald32(prog) < t - 64 && ++tr < (1 << 14)) __builtin_amdgcn_s_sleep(8); }
      // poll h0[t+1] row `wave` (proven tagged write-once protocol)
      const unsigned* src = h0u + (size_t)(t + 1) * 2560 + wave * HH;
      unsigned v[5]; int tries = 0;
      for (;;) {
#pragma unroll
        for (int j = 0; j < 5; j++) v[j] = ald32(src + j * 64 + lane);
        unsigned a = v[0] & v[1] & v[2] & v[3] & v[4];
        if (__all((int)(a & 1u)) || ++tries > (1 << 14)) break;
        __builtin_amdgcn_s_sleep(2);
      }
#pragma unroll
      for (int j = 0; j < 5; j++)
        hq[buf][wave][j * 64 + lane] = (char)__float2int_rn(bf2f(v[j]) * 127.f);
      asm volatile("s_waitcnt lgkmcnt(0)\n\ts_barrier" ::: "memory");

      const unsigned tg = (unsigned)((t & 255) + 1);
      const unsigned slot = (unsigned)((t & 127) * 10240);
#pragma unroll
      for (int P = 0; P < 2; P++) {
        i4v acc[5];
#pragma unroll
        for (int mi = 0; mi < 5; mi++) { i4v z = {0,0,0,0}; acc[mi] = z; }
#pragma unroll
        for (int kt = 0; kt < 5; kt++) {
          i4v bf = *(const i4v*)(&hq[buf][n16][kt * 64 + q * 16]);
#pragma unroll
          for (int mi = 0; mi < 5; mi++) {
            const int m = P ? mi : 5 + mi;
            const int gi = m * 5 + kt;
            i4v wf = (gi < 6) ? *(const i4v*)(&wlds[wave][gi][lane * 16]) : wreg[gi - 6];
            acc[mi] = __builtin_amdgcn_mfma_i32_16x16x64_i8(wf, bf, acc[mi], 0, 0, 0);
          }
        }
        if (n16 < BB) {
#pragma unroll
          for (int mi = 0; mi < 5; mi++) {
            const int m = P ? mi : 5 + mi;
#pragma unroll
            for (int r = 0; r < 4; r++) {
              const int gr = wave * 160 + m * 16 + q * 4 + r;
              const int g = gr / HH;              // constant divisor -> magic mul
              const int u = gr - g * HH;
              float z = (float)acc[mi][r] * kf + b1s[gr];
              ast32(z1u + slot + u * 32 + n16 * 4 + g, (((unsigned)f2bf(z)) << 16) | tg);
            }
          }
        }
      }
    }
  }
}

// ---------------- output projections: h bf16 [t][16][320] @ Wo^T -> out2[t][16][128] ----------------
__global__ __launch_bounds__(256) void proj_mfma(
    const ushort* __restrict__ hseq, const ushort* __restrict__ wo,
    const float* __restrict__ bo, float* __restrict__ out2)
{
  const int t = blockIdx.x;
  const int wave = threadIdx.x >> 6, lane = threadIdx.x & 63;
  const int q = lane >> 4, n16 = lane & 15;
  s8v a[10];
  const ushort* hp = hseq + (size_t)(t + 1) * 5120 + n16 * HH + q * 8;
#pragma unroll
  for (int kt = 0; kt < 10; kt++) a[kt] = *(const s8v*)(hp + kt * 32);
  for (int j = 0; j < 2; j++) {
    int nt = wave * 2 + j;
    s8v bf[10];
#pragma unroll
    for (int kt = 0; kt < 10; kt++)
      bf[kt] = *(const s8v*)(wo + (nt * 16 + n16) * HH + kt * 32 + q * 8);
    f4v acc = {0.f, 0.f, 0.f, 0.f};
#pragma unroll
    for (int kt = 0; kt < 10; kt++)
      acc = __builtin_amdgcn_mfma_f32_16x16x32_bf16(a[kt], bf[kt], acc, 0, 0, 0);
    int v = nt * 16 + n16;
    float bias = bo[v];
    if (q < 2) {
#pragma unroll
      for (int r = 0; r < 4; r++) {
        int b = 4 * q + r;                   // D row = batch
        out2[((size_t)t * 16 + b) * VV + v] = acc[r] + bias;
      }
    }
  }
}

// ---------------- per-cell logsumexp over V -> lb[b][t][u], ly[b][t][u] ----------------
__global__ __launch_bounds__(256) void lse_kernel(
    const float* __restrict__ enc2, const float* __restrict__ dec2,
    const int* __restrict__ ys, float* __restrict__ lb, float* __restrict__ ly)
{
  const int blk = blockIdx.x;                // 4000 = 8*500
  const int b = blk / TT, t = blk - b * TT;
  const int wave = threadIdx.x >> 6, lane = threadIdx.x & 63;
  const float* er = enc2 + ((size_t)t * 16 + b) * VV;
  const float e0 = er[lane], e1 = er[lane + 64];
  for (int u = wave; u < UP1; u += 4) {
    const float* dr = dec2 + ((size_t)u * 16 + b) * VV;
    float s0 = e0 + dr[lane], s1 = e1 + dr[lane + 64];
    float mx = fmaxf(s0, s1);
#pragma unroll
    for (int off = 32; off >= 1; off >>= 1) mx = fmaxf(mx, __shfl_xor(mx, off));
    float p = __expf(s0 - mx) + __expf(s1 - mx);
#pragma unroll
    for (int off = 32; off >= 1; off >>= 1) p += __shfl_xor(p, off);
    float lsev = mx + __logf(p);
    if (u < UU) {
      int y = ys[b * UU + u];                // in [1,127]
      float sy = (y < 64) ? __shfl(s0, y) : __shfl(s1, y - 64);
      if (lane == 0) ly[((size_t)b * TT + t) * UU + u] = sy - lsev;
    }
    if (lane == 0) lb[((size_t)b * TT + t) * UP1 + u] = s0 - lsev;
  }
}

// ---------------- forward DP: one wave per sample, barrier-free (shfl) ----------------
__global__ __launch_bounds__(64) void dp_kernel(
    const float* __restrict__ lb, const float* __restrict__ ly,
    const int* __restrict__ xlen, const int* __restrict__ ylen,
    float* __restrict__ out)
{
  const int b = blockIdx.x, l = threadIdx.x;
  const int tl = xlen[b], ul = ylen[b];
  const float NEG = -1e30f;
  const float* lbb = lb + (size_t)b * TT * UP1;
  const float* lyb = ly + (size_t)b * TT * UU;
  const int u1 = l, u2 = 64 + l;
  const bool has2 = (u2 <= UU);
  float a1 = (l == 0) ? 0.f : NEG, a2 = NEG;
  float nlb1 = 0.f, nly1 = 0.f, nlb2 = 0.f, nly2 = 0.f;
  { int tn = 1 - u1;
    if (tn >= 1 && tn < TT) nlb1 = lbb[(tn - 1) * UP1 + u1];
    if (u1 >= 1 && tn >= 0 && tn < TT) nly1 = lyb[tn * UU + (u1 - 1)]; }
  // (u2 >= 64 -> d=1 gives tn<0: nothing to prefetch)
  for (int d = 1; d <= TT - 1 + UU; d++) {
    float lb1 = nlb1, ly1 = nly1, lb2 = nlb2, ly2 = nly2;
    { int tn = d + 1 - u1;
      nlb1 = (tn >= 1 && tn < TT) ? lbb[(tn - 1) * UP1 + u1] : 0.f;
      nly1 = (u1 >= 1 && tn >= 0 && tn < TT) ? lyb[tn * UU + (u1 - 1)] : 0.f; }
    { int tn = d + 1 - u2;
      nlb2 = (has2 && tn >= 1 && tn < TT) ? lbb[(tn - 1) * UP1 + u2] : 0.f;
      nly2 = (has2 && tn >= 0 && tn < TT) ? lyb[tn * UU + (u2 - 1)] : 0.f; }
    float p1 = __shfl_up(a1, 1);
    float p2 = __shfl_up(a2, 1);
    float wz = __shfl(a1, 63);
    if (l == 0) p2 = wz;
    {
      const int t1 = d - u1;
      float v1 = NEG;
      if (t1 >= 0 && t1 < TT) {
        float x = (t1 >= 1) ? a1 + lb1 : NEG;
        float y = (u1 >= 1) ? p1 + ly1 : NEG;
        float m = fmaxf(x, y);
        v1 = (m <= -1e29f) ? NEG : m + __logf(1.f + __expf(-fabsf(x - y)));
        if (t1 == tl - 1 && u1 == ul) atomicAdd(out, -0.125f * (v1 + lbb[t1 * UP1 + u1]));
      }
      a1 = v1;
    }
    {
      const int t2 = d - u2;
      float v2 = NEG;
      if (has2 && t2 >= 0 && t2 < TT) {
        float x = (t2 >= 1) ? a2 + lb2 : NEG;
        float y = p2 + ly2;                  // u2 >= 64 >= 1 always
        float m = fmaxf(x, y);
        v2 = (m <= -1e29f) ? NEG : m + __logf(1.f + __expf(-fabsf(x - y)));
        if (t2 == tl - 1 && u2 == ul) atomicAdd(out, -0.125f * (v2 + lbb[t2 * UP1 + u2]));
      }
      a2 = v2;
    }
  }
}

// ---------------- launch ----------------
extern "C" void kernel_launch(void* const* d_in, const int* in_sizes, int n_in,
                              void* d_out, int out_size, void* d_ws, size_t ws_size,
                              hipStream_t stream) {
  (void)in_sizes; (void)n_in; (void)out_size;
  const float* xs    = (const float*)d_in[0];
  const int*   ys    = (const int*)d_in[1];
  const int*   xlen  = (const int*)d_in[2];
  const int*   ylen  = (const int*)d_in[3];
  const float* eWih0 = (const float*)d_in[4];
  const float* eWhh0 = (const float*)d_in[5];
  const float* ebih0 = (const float*)d_in[6];
  const float* ebhh0 = (const float*)d_in[7];
  const float* eWih1 = (const float*)d_in[8];
  const float* eWhh1 = (const float*)d_in[9];
  const float* ebih1 = (const float*)d_in[10];
  const float* ebhh1 = (const float*)d_in[11];
  const float* eWo   = (const float*)d_in[12];
  const float* ebo   = (const float*)d_in[13];
  const float* dWih  = (const float*)d_in[15];
  const float* dWhh  = (const float*)d_in[16];
  const float* dbih  = (const float*)d_in[17];
  const float* dbhh  = (const float*)d_in[18];
  const float* dWo   = (const float*)d_in[19];
  const float* dbo   = (const float*)d_in[20];

  char* ws = (char*)d_ws;
  const size_t OFF_CTL   = 0;                     // smax[4] at 0, prog at u32[16]
  const size_t OFF_XP0H  = 1024;                  // [8][500][1280] bf16
  const size_t OFF_XPD   = OFF_XP0H + 10240000;   // [8][121][1280] f32
  const size_t OFF_H0    = OFF_XPD  + 4956160;    // [501][8][320] tagged u32
  const size_t OFF_H1    = OFF_H0   + 5130240;    // [501][16][320] bf16 (rows 0-7 used)
  const size_t OFF_HD    = OFF_H1   + 5130240;    // [122][16][320] bf16
  const size_t OFF_WQ    = OFF_HD   + 1249280;    // i8 blobs [4][409600]
  const size_t OFF_WIH0B = OFF_WQ   + 1638400;
  const size_t OFF_XSB   = OFF_WIH0B + 245760;
  const size_t OFF_WOB   = OFF_XSB  + 768000;
  const size_t OFF_DWOB  = OFF_WOB  + 81920;
  const size_t OFF_B1S   = OFF_DWOB + 81920;
  const size_t OFF_B0S   = OFF_B1S  + 5120;
  const size_t OFF_EPI   = OFF_B0S  + 5120;       // enc2|dec2|lb|ly, z1 ring aliases
  const size_t OFF_ENC2  = OFF_EPI;               // 500*16*128 f32 = 4,096,000
  const size_t OFF_DEC2  = OFF_ENC2 + 4096000;    // 121*16*128 f32 =   991,232
  const size_t OFF_LB    = OFF_DEC2 + 991232;     // 8*500*121 f32  = 1,936,000
  const size_t OFF_LY    = OFF_LB   + 1936000;    // 8*500*120 f32  = 1,920,000
  const size_t TOTAL     = OFF_LY   + 1920000;    // ~38.5 MB (< r4's proven 40.6)
  if (ws_size < TOTAL) return;

  unsigned* ctl   = (unsigned*)(ws + OFF_CTL);
  unsigned* smax  = ctl;
  unsigned* prog  = ctl + 16;
  ushort*   xp0h  = (ushort*)(ws + OFF_XP0H);
  float*    xpd   = (float*)(ws + OFF_XPD);
  unsigned* h0    = (unsigned*)(ws + OFF_H0);
  ushort*   h1    = (ushort*)(ws + OFF_H1);
  ushort*   hd    = (ushort*)(ws + OFF_HD);
  char*     wq    = (char*)(ws + OFF_WQ);
  ushort*   wih0b = (ushort*)(ws + OFF_WIH0B);
  ushort*   xsb   = (ushort*)(ws + OFF_XSB);
  ushort*   wob   = (ushort*)(ws + OFF_WOB);
  ushort*   dwob  = (ushort*)(ws + OFF_DWOB);
  float*    b1s   = (float*)(ws + OFF_B1S);
  float*    b0s   = (float*)(ws + OFF_B0S);
  float*    enc2  = (float*)(ws + OFF_ENC2);
  float*    dec2  = (float*)(ws + OFF_DEC2);
  float*    lb    = (float*)(ws + OFF_LB);
  float*    ly    = (float*)(ws + OFF_LY);
  unsigned* z1    = (unsigned*)(ws + OFF_EPI);    // 128-slot ring, 5.24 MB, pre-epilogue only
  float*    out   = (float*)d_out;

  hipLaunchKernelGGL(prep_zero, dim3(1), dim3(256), 0, stream, ctl, out);
  hipLaunchKernelGGL(k_absmax, dim3(1600), dim3(256), 0, stream,
                     eWhh0, eWhh1, dWhh, eWih1, smax);
  hipLaunchKernelGGL(k_pack, dim3(6400), dim3(256), 0, stream,
                     eWhh0, eWhh1, dWhh, eWih1, smax, wq);
  hipLaunchKernelGGL(prep_w, dim3(2310), dim3(256), 0, stream,
                     eWih0, xs, eWo, dWo, ebih1, ebhh1, ebih0, ebhh0,
                     wih0b, xsb, wob, dwob, b1s, b0s);
  hipLaunchKernelGGL(xproj0_mfma, dim3(250), dim3(256), 0, stream, xsb, wih0b, b0s, xp0h);
  hipLaunchKernelGGL(xprojd_g, dim3(968), dim3(256), 0, stream, ys, dWih, dbih, dbhh, xpd);
  hipLaunchKernelGGL(lstm_fused, dim3(6), dim3(512), 0, stream,
                     wq, smax, xp0h, xpd, b1s, h0, h1, hd, z1, prog);
  hipLaunchKernelGGL(proj_mfma, dim3(500), dim3(256), 0, stream, h1, wob, ebo, enc2);
  hipLaunchKernelGGL(proj_mfma, dim3(121), dim3(256), 0, stream, hd, dwob, dbo, dec2);
  hipLaunchKernelGGL(lse_kernel, dim3(4000), dim3(256), 0, stream, enc2, dec2, ys, lb, ly);
  hipLaunchKernelGGL(dp_kernel, dim3(8), dim3(64), 0, stream, lb, ly, xlen, ylen, out);
}

// Round 6
// 5982.903 us; speedup vs baseline: 7.4055x; 7.4055x over previous
//
#include <hip/hip_runtime.h>

typedef __attribute__((ext_vector_type(8))) short s8v;   // 8 x bf16 (4 VGPRs)
typedef __attribute__((ext_vector_type(4))) float f4v;   // f32 MFMA accumulator
typedef __attribute__((ext_vector_type(4))) int   i4v;   // i8 MFMA operand/accumulator

#define BB 8
#define TT 500
#define UU 120
#define UP1 121
#define VV 128
#define HH 320
#define G4 1280

// ---------------- helpers ----------------
__device__ __forceinline__ unsigned short f2bf(float x) {
  unsigned u = __builtin_bit_cast(unsigned, x);
  unsigned r = (u + 0x7FFFu + ((u >> 16) & 1u)) >> 16;  // RNE
  return (unsigned short)r;
}
__device__ __forceinline__ float bf2f(unsigned hi16) {  // bf16 in high 16 bits
  return __builtin_bit_cast(float, hi16 & 0xFFFF0000u);
}
__device__ __forceinline__ float sigf(float x)   { return 1.f / (1.f + __expf(-x)); }
__device__ __forceinline__ float tanh_f(float x) { return 2.f / (1.f + __expf(-2.f * x)) - 1.f; }

// relaxed agent-scope atomics (sc1 path; proven transport r3/r4)
__device__ __forceinline__ unsigned ald32(const unsigned* p) {
  return __hip_atomic_load((unsigned*)p, __ATOMIC_RELAXED, __HIP_MEMORY_SCOPE_AGENT);
}
__device__ __forceinline__ void ast32(unsigned* p, unsigned v) {
  __hip_atomic_store(p, v, __ATOMIC_RELAXED, __HIP_MEMORY_SCOPE_AGENT);
}

// ---------------- prep: zero control words + out ----------------
__global__ void prep_zero(unsigned* ctl, float* out) {
  int i = blockIdx.x * blockDim.x + threadIdx.x;
  if (i < 256) ctl[i] = 0u;          // smax[0..3] at [0..4), prog at [16]
  if (i == 0) out[0] = 0.f;
}

// ---------------- abs-max per recurrent matrix (for i8 scales) ----------------
__global__ __launch_bounds__(256) void k_absmax(
    const float* __restrict__ w0, const float* __restrict__ w1,
    const float* __restrict__ w2, const float* __restrict__ w3,
    unsigned* __restrict__ smax)
{
  const int blk = blockIdx.x;                 // 1600 = 4 mats x 400
  const int s = blk / 400;
  const int off = (blk - s * 400) * 1024 + threadIdx.x * 4;
  const float* src = (s == 0) ? w0 : (s == 1) ? w1 : (s == 2) ? w2 : w3;
  float m = 0.f;
#pragma unroll
  for (int j = 0; j < 4; j++) m = fmaxf(m, fabsf(src[off + j]));
#pragma unroll
  for (int o = 32; o >= 1; o >>= 1) m = fmaxf(m, __shfl_xor(m, o));
  if ((threadIdx.x & 63) == 0) atomicMax(smax + s, __float_as_uint(m));
}

// ---------------- pack recurrent matrices into per-wave i8 MFMA fragment blobs ----------------
// blob[s][w][mt][kt][lane][16] i8 ; s: 0=Whh0 1=Whh1 2=Whhd 3=Wih1  (r5-verified)
__global__ __launch_bounds__(256) void k_pack(
    const float* __restrict__ w0, const float* __restrict__ w1,
    const float* __restrict__ w2, const float* __restrict__ w3,
    const unsigned* __restrict__ smax, char* __restrict__ wq)
{
  int gid = blockIdx.x * 256 + threadIdx.x;
  if (gid >= 1638400) return;
  int s = gid / 409600, r = gid - s * 409600;
  int j = r & 15, ln = (r >> 4) & 63, rem = r >> 10;
  int kt = rem % 5, mt = (rem / 5) % 10, w = rem / 50;
  int qq = ln >> 4, nn = ln & 15;
  int k = kt * 64 + qq * 16 + j;
  int gr;
  if (s < 3) { int unit = w * 40 + mt * 4 + (nn >> 2); gr = (nn & 3) * HH + unit; }
  else       { gr = w * 160 + mt * 16 + nn; }
  const float* src = (s == 0) ? w0 : (s == 1) ? w1 : (s == 2) ? w2 : w3;
  float inv = 127.f / __uint_as_float(smax[s]);
  wq[gid] = (char)__float2int_rn(src[gr * HH + k] * inv);
}

// ---------------- misc prep: bf16 staging + bias folds ----------------
__global__ void prep_w(
    const float* __restrict__ wih0, const float* __restrict__ xs,
    const float* __restrict__ ewo,  const float* __restrict__ dwo,
    const float* __restrict__ bih1, const float* __restrict__ bhh1,
    const float* __restrict__ bih0, const float* __restrict__ bhh0,
    ushort* __restrict__ wih0b, ushort* __restrict__ xsb,
    ushort* __restrict__ wob, ushort* __restrict__ dwob,
    float* __restrict__ b1s, float* __restrict__ b0s)
{
  int i = blockIdx.x * blockDim.x + threadIdx.x;
  if (i < 122880) {                        // Wih0 [1280][80] -> [1280][96] padded
    int row = i / 96, k = i - row * 96;
    wih0b[i] = (k < 80) ? f2bf(wih0[row * 80 + k]) : (ushort)0;
  } else if (i < 506880) {                 // xs [4000][80] -> [4000][96] padded
    int e = i - 122880;
    int row = e / 96, k = e - row * 96;
    xsb[e] = (k < 80) ? f2bf(xs[row * 80 + k]) : (ushort)0;
  } else if (i < 547840) {                 // enc_Wo [128][320]
    wob[i - 506880] = f2bf(ewo[i - 506880]);
  } else if (i < 588800) {                 // dec_Wo [128][320]
    dwob[i - 547840] = f2bf(dwo[i - 547840]);
  } else if (i < 590080) {                 // b1s[gr] = bih1+bhh1 (gate-row order)
    int e = i - 588800;
    b1s[e] = bih1[e] + bhh1[e];
  } else if (i < 591360) {                 // b0s[gr]
    int e = i - 590080;
    b0s[e] = bih0[e] + bhh0[e];
  }
}

// ---------------- xproj layer0 (bf16 MFMA, r1-verified), bf16 out ----------------
__global__ __launch_bounds__(256) void xproj0_mfma(
    const ushort* __restrict__ xsb, const ushort* __restrict__ wih0b,
    const float* __restrict__ b0s, ushort* __restrict__ xp0h)
{
  const int mt = blockIdx.x;                 // 250 tiles of 16 (b,t)-rows
  const int wave = threadIdx.x >> 6, lane = threadIdx.x & 63;
  const int q = lane >> 4, n16 = lane & 15;
  s8v a[3];
#pragma unroll
  for (int kt = 0; kt < 3; kt++)
    a[kt] = *(const s8v*)(xsb + (mt * 16 + n16) * 96 + kt * 32 + q * 8);
  for (int nt = wave; nt < 80; nt += 4) {
    s8v bf[3];
#pragma unroll
    for (int kt = 0; kt < 3; kt++)
      bf[kt] = *(const s8v*)(wih0b + (nt * 16 + n16) * 96 + kt * 32 + q * 8);
    f4v acc = {0.f, 0.f, 0.f, 0.f};
#pragma unroll
    for (int kt = 0; kt < 3; kt++)
      acc = __builtin_amdgcn_mfma_f32_16x16x32_bf16(a[kt], bf[kt], acc, 0, 0, 0);
    const int gr = nt * 16 + n16;            // D col = gate row
    const int gg = gr / HH;
    const int uu = gr - gg * HH;
    const float bias = b0s[gr];
#pragma unroll
    for (int r = 0; r < 4; r++) {
      int bt = mt * 16 + 4 * q + r;          // D row = (b,t) row
      xp0h[(size_t)bt * G4 + uu * 4 + gg] = f2bf(acc[r] + bias);
    }
  }
}

// ---------------- decoder input projection: one-hot gather, bf16 out ----------------
__global__ __launch_bounds__(256) void xprojd_g(
    const int* __restrict__ ys, const float* __restrict__ dWih,
    const float* __restrict__ dbih, const float* __restrict__ dbhh,
    ushort* __restrict__ xpdh)
{
  const int blk = blockIdx.x;                // 968 = 8 * 121
  const int b = blk / UP1, u = blk - b * UP1;
  int colv = -1;
  if (u > 0) colv = ys[b * UU + (u - 1)] - 1;
  for (int i = threadIdx.x; i < G4; i += 256) {
    int uu = i >> 2, gg = i & 3;
    int row = gg * HH + uu;
    float v = dbih[row] + dbhh[row];
    if (colv >= 0) v += dWih[row * 127 + colv];
    xpdh[((size_t)b * UP1 + u) * G4 + i] = f2bf(v);
  }
}

// ---------------- fused recurrences: 6 wgs, recurrences INTRA-workgroup (r5 topology) ----------------
// role 0: L0  (i8 Whh0 resident; publishes h0 tagged u32 — proven write-once LSB protocol)
// role 1: L1  (i8 Whh1 resident; wave-sliced coalesced z1 relay -> LDS; publishes h1 bf16)
// role 2: dec (i8 Whhd resident; publishes hd bf16), 121 steps
// role 3..5: z1 producers (t mod 3): poll h0[t+1], z1[t]=Wih1@h0[t+1]+b1 -> 256-slot ring,
//            2-bit generation tags (poison-proof), coarse prog throttle (no reuse hazard).
__global__ __launch_bounds__(512) void lstm_fused(
    const char* __restrict__ wq, const unsigned* __restrict__ smaxp,
    const ushort* __restrict__ xp0h, const ushort* __restrict__ xpdh,
    const float* __restrict__ b1s,
    unsigned* __restrict__ h0u, ushort* __restrict__ h1h, ushort* __restrict__ hdh,
    unsigned* __restrict__ z1u, unsigned* __restrict__ prog)
{
  const int role = blockIdx.x;
  const int tid = threadIdx.x;
  const int wave = tid >> 6, lane = tid & 63;
  const int q = lane >> 4, n16 = lane & 15;
  const int bcol = n16 & 7;
  const int ub = wave * 40;                  // rec roles: this wave owns units [ub,ub+40)

  __shared__ __align__(16) char wlds[8][4][1024];     // 32 KB: frag-groups gi 0..3 per wave
  __shared__ __align__(16) ushort zb[10240];          // 20 KB: z1[t] addends (bf16), L1 only
  __shared__ __align__(16) char hq[2][16][336];       // 10.75 KB: dbuf h_i8 (B operand)

  const int mat = (role <= 2) ? role : 3;
  const char* blob = wq + mat * 409600 + wave * 51200;

  // ---- startup: weights into regs (gi 4..49) + LDS (gi 0..3); zero hq ----
  i4v wreg[46];
#pragma unroll
  for (int gi = 4; gi < 50; gi++)
    wreg[gi - 4] = *(const i4v*)(blob + gi * 1024 + lane * 16);
#pragma unroll
  for (int gi = 0; gi < 4; gi++) {
    i4v v = *(const i4v*)(blob + gi * 1024 + lane * 16);
    *(i4v*)(&wlds[wave][gi][lane * 16]) = v;
  }
  for (int i = tid; i < 2688; i += 512) ((unsigned*)hq)[i] = 0u;
  __syncthreads();

  const float kf = __uint_as_float(smaxp[mat]) * (1.f / 16129.f);  // smax/(127*127)

  if (role <= 2) {
    // ================= recurrent stages =================
    const int steps = (role == 2) ? UP1 : TT;
    const ushort* xq = (role == 0) ? (xp0h + (size_t)bcol * TT * G4)
                                   : (xpdh + (size_t)bcol * UP1 * G4);
    float c[10];
#pragma unroll
    for (int m = 0; m < 10; m++) c[m] = 0.f;

    for (int t = 0; t < steps; t++) {
      const int pb = t & 1;

      if (role == 1) {
        // ---- wave-sliced coalesced relay of z1[t] into LDS (r4-proven pattern) ----
        const unsigned tv = (((unsigned)(t >> 8)) << 1) | 1u;
        const unsigned* zsrc = z1u + (unsigned)((t & 255) * 10240) + wave * 1280;
        unsigned v[20];
        int tries = 0;
        for (;;) {
#pragma unroll
          for (int k = 0; k < 20; k++) v[k] = ald32(zsrc + k * 64 + lane);
          unsigned a = v[0];
#pragma unroll
          for (int k = 1; k < 20; k++) a &= v[k];
          if (__all((int)((a & 3u) == tv)) || ++tries > (1 << 17)) break;
          __builtin_amdgcn_s_sleep(2);
        }
#pragma unroll
        for (int k = 0; k < 20; k++)
          zb[wave * 1280 + k * 64 + lane] = (ushort)(v[k] >> 16);
        asm volatile("s_waitcnt lgkmcnt(0)\n\ts_barrier" ::: "memory");
      }

#pragma unroll
      for (int P = 0; P < 2; P++) {
        // P=0: mts 5..9 (all-reg weights); P=1: mts 0..4 (gi<4 from LDS)
        uint2 xa[5];
#pragma unroll
        for (int mi = 0; mi < 5; mi++) {
          const int m = P ? mi : 5 + mi;
          const int u = ub + m * 4 + q;
          if (role == 1) xa[mi] = *(const uint2*)&zb[u * 32 + (n16 & 7) * 4];
          else           xa[mi] = *(const uint2*)(xq + (size_t)t * G4 + u * 4);
        }

        i4v acc[5];
#pragma unroll
        for (int mi = 0; mi < 5; mi++) { i4v z = {0, 0, 0, 0}; acc[mi] = z; }
#pragma unroll
        for (int kt = 0; kt < 5; kt++) {
          i4v bf = *(const i4v*)(&hq[pb][n16][kt * 64 + q * 16]);
#pragma unroll
          for (int mi = 0; mi < 5; mi++) {
            const int m = P ? mi : 5 + mi;
            const int gi = m * 5 + kt;
            i4v wf = (gi < 4) ? *(const i4v*)(&wlds[wave][gi][lane * 16]) : wreg[gi - 4];
            acc[mi] = __builtin_amdgcn_mfma_i32_16x16x64_i8(wf, bf, acc[mi], 0, 0, 0);
          }
        }

        // ---- cell: lane-local (unit = ub+m*4+q, batch n16); addend = 4 bf16 in xa ----
#pragma unroll
        for (int mi = 0; mi < 5; mi++) {
          const int m = P ? mi : 5 + mi;
          float ad0 = bf2f(xa[mi].x << 16), ad1 = bf2f(xa[mi].x);
          float ad2 = bf2f(xa[mi].y << 16), ad3 = bf2f(xa[mi].y);
          float p0 = (float)acc[mi][0] * kf + ad0;
          float p1 = (float)acc[mi][1] * kf + ad1;
          float p2 = (float)acc[mi][2] * kf + ad2;
          float p3 = (float)acc[mi][3] * kf + ad3;
          float ig = sigf(p0), fg = sigf(p1), gv = tanh_f(p2), og = sigf(p3);
          c[m] = fg * c[m] + ig * gv;
          float hv = og * tanh_f(c[m]);
          const int u = ub + m * 4 + q;
          hq[pb ^ 1][n16][u] = (char)__float2int_rn(hv * 127.f);
          if (n16 < BB) {
            unsigned hb = (unsigned)f2bf(hv);
            if (role == 0)
              ast32(h0u + (size_t)(t + 1) * 2560 + n16 * HH + u, (hb << 16) | 1u);
            else if (role == 1)
              h1h[(size_t)(t + 1) * 5120 + n16 * HH + u] = (ushort)hb;
            else
              hdh[(size_t)(t + 1) * 5120 + n16 * HH + u] = (ushort)hb;
          }
        }
      }
      // LDS-only barrier (no vmcnt drain; publishes fire-and-forget)
      asm volatile("s_waitcnt lgkmcnt(0)\n\ts_barrier" ::: "memory");
      if (role == 1 && (t & 15) == 0 && tid == 0) ast32(prog, (unsigned)t);
    }
  } else {
    // ================= z1 producers (t = p3, p3+3, ...) =================
    const int p3 = role - 3;
    int it = 0;
    for (int t = p3; t < TT; t += 3, it++) {
      const int buf = it & 1;
      // coarse throttle: stay < 192 steps ahead of L1 (ring reuse at 256)
      { int tr = 0;
        while ((int)ald32(prog) < t - 192 && ++tr < (1 << 15)) __builtin_amdgcn_s_sleep(8); }
      // poll h0[t+1] row `wave` (proven tagged write-once protocol)
      const unsigned* src = h0u + (size_t)(t + 1) * 2560 + wave * HH;
      unsigned v[5]; int tries = 0;
      for (;;) {
#pragma unroll
        for (int j = 0; j < 5; j++) v[j] = ald32(src + j * 64 + lane);
        unsigned a = v[0] & v[1] & v[2] & v[3] & v[4];
        if (__all((int)(a & 1u)) || ++tries > (1 << 17)) break;
        __builtin_amdgcn_s_sleep(2);
      }
#pragma unroll
      for (int j = 0; j < 5; j++)
        hq[buf][wave][j * 64 + lane] = (char)__float2int_rn(bf2f(v[j]) * 127.f);
      asm volatile("s_waitcnt lgkmcnt(0)\n\ts_barrier" ::: "memory");

      const unsigned tv = (((unsigned)(t >> 8)) << 1) | 1u;
      const unsigned slot = (unsigned)((t & 255) * 10240);
#pragma unroll
      for (int P = 0; P < 2; P++) {
        i4v acc[5];
#pragma unroll
        for (int mi = 0; mi < 5; mi++) { i4v z = {0, 0, 0, 0}; acc[mi] = z; }
#pragma unroll
        for (int kt = 0; kt < 5; kt++) {
          i4v bf = *(const i4v*)(&hq[buf][n16][kt * 64 + q * 16]);
#pragma unroll
          for (int mi = 0; mi < 5; mi++) {
            const int m = P ? mi : 5 + mi;
            const int gi = m * 5 + kt;
            i4v wf = (gi < 4) ? *(const i4v*)(&wlds[wave][gi][lane * 16]) : wreg[gi - 4];
            acc[mi] = __builtin_amdgcn_mfma_i32_16x16x64_i8(wf, bf, acc[mi], 0, 0, 0);
          }
        }
        if (n16 < BB) {
#pragma unroll
          for (int mi = 0; mi < 5; mi++) {
            const int m = P ? mi : 5 + mi;
#pragma unroll
            for (int r = 0; r < 4; r++) {
              const int gr = wave * 160 + m * 16 + q * 4 + r;  // D row = gate-row (r5-verified)
              const int g = gr / HH;
              const int u = gr - g * HH;
              float z = (float)acc[mi][r] * kf + b1s[gr];
              ast32(z1u + slot + u * 32 + n16 * 4 + g, (((unsigned)f2bf(z)) << 16) | tv);
            }
          }
        }
      }
    }
  }
}

// ---------------- output projections: h bf16 [t][16][320] @ Wo^T -> out2[t][16][128] ----------------
__global__ __launch_bounds__(256) void proj_mfma(
    const ushort* __restrict__ hseq, const ushort* __restrict__ wo,
    const float* __restrict__ bo, float* __restrict__ out2)
{
  const int t = blockIdx.x;
  const int wave = threadIdx.x >> 6, lane = threadIdx.x & 63;
  const int q = lane >> 4, n16 = lane & 15;
  s8v a[10];
  const ushort* hp = hseq + (size_t)(t + 1) * 5120 + n16 * HH + q * 8;
#pragma unroll
  for (int kt = 0; kt < 10; kt++) a[kt] = *(const s8v*)(hp + kt * 32);
  for (int j = 0; j < 2; j++) {
    int nt = wave * 2 + j;
    s8v bf[10];
#pragma unroll
    for (int kt = 0; kt < 10; kt++)
      bf[kt] = *(const s8v*)(wo + (nt * 16 + n16) * HH + kt * 32 + q * 8);
    f4v acc = {0.f, 0.f, 0.f, 0.f};
#pragma unroll
    for (int kt = 0; kt < 10; kt++)
      acc = __builtin_amdgcn_mfma_f32_16x16x32_bf16(a[kt], bf[kt], acc, 0, 0, 0);
    int v = nt * 16 + n16;
    float bias = bo[v];
    if (q < 2) {
#pragma unroll
      for (int r = 0; r < 4; r++) {
        int b = 4 * q + r;                   // D row = batch
        out2[((size_t)t * 16 + b) * VV + v] = acc[r] + bias;
      }
    }
  }
}

// ---------------- per-cell logsumexp over V -> lb[b][t][u], ly[b][t][u] ----------------
__global__ __launch_bounds__(256) void lse_kernel(
    const float* __restrict__ enc2, const float* __restrict__ dec2,
    const int* __restrict__ ys, float* __restrict__ lb, float* __restrict__ ly)
{
  const int blk = blockIdx.x;                // 4000 = 8*500
  const int b = blk / TT, t = blk - b * TT;
  const int wave = threadIdx.x >> 6, lane = threadIdx.x & 63;
  const float* er = enc2 + ((size_t)t * 16 + b) * VV;
  const float e0 = er[lane], e1 = er[lane + 64];
  for (int u = wave; u < UP1; u += 4) {
    const float* dr = dec2 + ((size_t)u * 16 + b) * VV;
    float s0 = e0 + dr[lane], s1 = e1 + dr[lane + 64];
    float mx = fmaxf(s0, s1);
#pragma unroll
    for (int off = 32; off >= 1; off >>= 1) mx = fmaxf(mx, __shfl_xor(mx, off));
    float p = __expf(s0 - mx) + __expf(s1 - mx);
#pragma unroll
    for (int off = 32; off >= 1; off >>= 1) p += __shfl_xor(p, off);
    float lsev = mx + __logf(p);
    if (u < UU) {
      int y = ys[b * UU + u];                // in [1,127]
      float sy = (y < 64) ? __shfl(s0, y) : __shfl(s1, y - 64);
      if (lane == 0) ly[((size_t)b * TT + t) * UU + u] = sy - lsev;
    }
    if (lane == 0) lb[((size_t)b * TT + t) * UP1 + u] = s0 - lsev;
  }
}

// ---------------- forward DP: one wave per sample, barrier-free (shfl) ----------------
__global__ __launch_bounds__(64) void dp_kernel(
    const float* __restrict__ lb, const float* __restrict__ ly,
    const int* __restrict__ xlen, const int* __restrict__ ylen,
    float* __restrict__ out)
{
  const int b = blockIdx.x, l = threadIdx.x;
  const int tl = xlen[b], ul = ylen[b];
  const float NEG = -1e30f;
  const float* lbb = lb + (size_t)b * TT * UP1;
  const float* lyb = ly + (size_t)b * TT * UU;
  const int u1 = l, u2 = 64 + l;
  const bool has2 = (u2 <= UU);
  float a1 = (l == 0) ? 0.f : NEG, a2 = NEG;
  float nlb1 = 0.f, nly1 = 0.f, nlb2 = 0.f, nly2 = 0.f;
  { int tn = 1 - u1;
    if (tn >= 1 && tn < TT) nlb1 = lbb[(tn - 1) * UP1 + u1];
    if (u1 >= 1 && tn >= 0 && tn < TT) nly1 = lyb[tn * UU + (u1 - 1)]; }
  for (int d = 1; d <= TT - 1 + UU; d++) {
    float lb1 = nlb1, ly1 = nly1, lb2 = nlb2, ly2 = nly2;
    { int tn = d + 1 - u1;
      nlb1 = (tn >= 1 && tn < TT) ? lbb[(tn - 1) * UP1 + u1] : 0.f;
      nly1 = (u1 >= 1 && tn >= 0 && tn < TT) ? lyb[tn * UU + (u1 - 1)] : 0.f; }
    { int tn = d + 1 - u2;
      nlb2 = (has2 && tn >= 1 && tn < TT) ? lbb[(tn - 1) * UP1 + u2] : 0.f;
      nly2 = (has2 && tn >= 0 && tn < TT) ? lyb[tn * UU + (u2 - 1)] : 0.f; }
    float p1 = __shfl_up(a1, 1);
    float p2 = __shfl_up(a2, 1);
    float wz = __shfl(a1, 63);
    if (l == 0) p2 = wz;
    {
      const int t1 = d - u1;
      float v1 = NEG;
      if (t1 >= 0 && t1 < TT) {
        float x = (t1 >= 1) ? a1 + lb1 : NEG;
        float y = (u1 >= 1) ? p1 + ly1 : NEG;
        float m = fmaxf(x, y);
        v1 = (m <= -1e29f) ? NEG : m + __logf(1.f + __expf(-fabsf(x - y)));
        if (t1 == tl - 1 && u1 == ul) atomicAdd(out, -0.125f * (v1 + lbb[t1 * UP1 + u1]));
      }
      a1 = v1;
    }
    {
      const int t2 = d - u2;
      float v2 = NEG;
      if (has2 && t2 >= 0 && t2 < TT) {
        float x = (t2 >= 1) ? a2 + lb2 : NEG;
        float y = p2 + ly2;
        float m = fmaxf(x, y);
        v2 = (m <= -1e29f) ? NEG : m + __logf(1.f + __expf(-fabsf(x - y)));
        if (t2 == tl - 1 && u2 == ul) atomicAdd(out, -0.125f * (v2 + lbb[t2 * UP1 + u2]));
      }
      a2 = v2;
    }
  }
}

// ---------------- launch ----------------
extern "C" void kernel_launch(void* const* d_in, const int* in_sizes, int n_in,
                              void* d_out, int out_size, void* d_ws, size_t ws_size,
                              hipStream_t stream) {
  (void)in_sizes; (void)n_in; (void)out_size;
  const float* xs    = (const float*)d_in[0];
  const int*   ys    = (const int*)d_in[1];
  const int*   xlen  = (const int*)d_in[2];
  const int*   ylen  = (const int*)d_in[3];
  const float* eWih0 = (const float*)d_in[4];
  const float* eWhh0 = (const float*)d_in[5];
  const float* ebih0 = (const float*)d_in[6];
  const float* ebhh0 = (const float*)d_in[7];
  const float* eWih1 = (const float*)d_in[8];
  const float* eWhh1 = (const float*)d_in[9];
  const float* ebih1 = (const float*)d_in[10];
  const float* ebhh1 = (const float*)d_in[11];
  const float* eWo   = (const float*)d_in[12];
  const float* ebo   = (const float*)d_in[13];
  const float* dWih  = (const float*)d_in[15];
  const float* dWhh  = (const float*)d_in[16];
  const float* dbih  = (const float*)d_in[17];
  const float* dbhh  = (const float*)d_in[18];
  const float* dWo   = (const float*)d_in[19];
  const float* dbo   = (const float*)d_in[20];

  char* ws = (char*)d_ws;
  const size_t OFF_CTL   = 0;                     // smax[4] at 0, prog at u32[16]
  const size_t OFF_XP0H  = 1024;                  // [8][500][1280] bf16
  const size_t OFF_XPDH  = OFF_XP0H + 10240000;   // [8][121][1280] bf16
  const size_t OFF_H0    = OFF_XPDH + 2478080;    // [501][8][320] tagged u32
  const size_t OFF_H1    = OFF_H0   + 5130240;    // [501][16][320] bf16 (rows 0-7 used)
  const size_t OFF_HD    = OFF_H1   + 5130240;    // [122][16][320] bf16
  const size_t OFF_WQ    = OFF_HD   + 1249280;    // i8 blobs [4][409600]
  const size_t OFF_WIH0B = OFF_WQ   + 1638400;
  const size_t OFF_XSB   = OFF_WIH0B + 245760;
  const size_t OFF_WOB   = OFF_XSB  + 768000;
  const size_t OFF_DWOB  = OFF_WOB  + 81920;
  const size_t OFF_B1S   = OFF_DWOB + 81920;
  const size_t OFF_B0S   = OFF_B1S  + 5120;
  const size_t OFF_SHR   = OFF_B0S  + 5120;       // z1 ring (pre-epi) aliases epi bufs
  const size_t OFF_ENC2  = OFF_SHR;               // 500*16*128 f32 = 4,096,000
  const size_t OFF_DEC2  = OFF_ENC2 + 4096000;    // 121*16*128 f32 =   991,232
  const size_t OFF_LB    = OFF_DEC2 + 991232;     // 8*500*121 f32  = 1,936,000
  const size_t OFF_LY    = OFF_LB   + 1936000;    // 8*500*120 f32  = 1,920,000
  const size_t EPI_END   = OFF_LY   + 1920000;    // = OFF_SHR + 8,943,232
  const size_t Z1_END    = OFF_SHR  + 10485760;   // 256 slots x 40 KB
  const size_t TOTAL     = (EPI_END > Z1_END) ? EPI_END : Z1_END;   // ~37.5 MB
  if (ws_size < TOTAL) return;

  unsigned* ctl   = (unsigned*)(ws + OFF_CTL);
  unsigned* smax  = ctl;
  unsigned* prog  = ctl + 16;
  ushort*   xp0h  = (ushort*)(ws + OFF_XP0H);
  ushort*   xpdh  = (ushort*)(ws + OFF_XPDH);
  unsigned* h0    = (unsigned*)(ws + OFF_H0);
  ushort*   h1    = (ushort*)(ws + OFF_H1);
  ushort*   hd    = (ushort*)(ws + OFF_HD);
  char*     wq    = (char*)(ws + OFF_WQ);
  ushort*   wih0b = (ushort*)(ws + OFF_WIH0B);
  ushort*   xsb   = (ushort*)(ws + OFF_XSB);
  ushort*   wob   = (ushort*)(ws + OFF_WOB);
  ushort*   dwob  = (ushort*)(ws + OFF_DWOB);
  float*    b1s   = (float*)(ws + OFF_B1S);
  float*    b0s   = (float*)(ws + OFF_B0S);
  float*    enc2  = (float*)(ws + OFF_ENC2);
  float*    dec2  = (float*)(ws + OFF_DEC2);
  float*    lb    = (float*)(ws + OFF_LB);
  float*    ly    = (float*)(ws + OFF_LY);
  unsigned* z1    = (unsigned*)(ws + OFF_SHR);
  float*    out   = (float*)d_out;

  hipLaunchKernelGGL(prep_zero, dim3(1), dim3(256), 0, stream, ctl, out);
  hipLaunchKernelGGL(k_absmax, dim3(1600), dim3(256), 0, stream,
                     eWhh0, eWhh1, dWhh, eWih1, smax);
  hipLaunchKernelGGL(k_pack, dim3(6400), dim3(256), 0, stream,
                     eWhh0, eWhh1, dWhh, eWih1, smax, wq);
  hipLaunchKernelGGL(prep_w, dim3(2310), dim3(256), 0, stream,
                     eWih0, xs, eWo, dWo, ebih1, ebhh1, ebih0, ebhh0,
                     wih0b, xsb, wob, dwob, b1s, b0s);
  hipLaunchKernelGGL(xproj0_mfma, dim3(250), dim3(256), 0, stream, xsb, wih0b, b0s, xp0h);
  hipLaunchKernelGGL(xprojd_g, dim3(968), dim3(256), 0, stream, ys, dWih, dbih, dbhh, xpdh);
  hipLaunchKernelGGL(lstm_fused, dim3(6), dim3(512), 0, stream,
                     wq, smax, xp0h, xpdh, b1s, h0, h1, hd, z1, prog);
  hipLaunchKernelGGL(proj_mfma, dim3(500), dim3(256), 0, stream, h1, wob, ebo, enc2);
  hipLaunchKernelGGL(proj_mfma, dim3(121), dim3(256), 0, stream, hd, dwob, dbo, dec2);
  hipLaunchKernelGGL(lse_kernel, dim3(4000), dim3(256), 0, stream, enc2, dec2, ys, lb, ly);
  hipLaunchKernelGGL(dp_kernel, dim3(8), dim3(64), 0, stream, lb, ly, xlen, ylen, out);
}